// Round 1
// baseline (509.405 us; speedup 1.0000x reference)
//
#include <hip/hip_runtime.h>
#include <hip/hip_bf16.h>
#include <math.h>

#define NV 50257
#define NE 256
#define NC 48
#define NB 64
#define NT 1024
#define L2E 1.44269504088896340736f
#define LN2 0.69314718055994530942f

// ---------------------------------------------------------------------------
// Kernel 1: logits[b,t,c] = emb_table[x[b,t]] . fc_w[c] + fc_b[c]
// One lane per token; fc_w read at wave-uniform addresses (scalar broadcast).
// ---------------------------------------------------------------------------
__global__ __launch_bounds__(64) void logits_kernel(
    const int* __restrict__ x,
    const float* __restrict__ emb,
    const float* __restrict__ w,
    const float* __restrict__ bias,
    float* __restrict__ out)
{
    const int token = blockIdx.x * 64 + threadIdx.x;
    const int idx = x[token];
    const float* __restrict__ row = emb + (size_t)idx * NE;

    float acc[NC];
#pragma unroll
    for (int c = 0; c < NC; ++c) acc[c] = bias[c];

#pragma unroll 1
    for (int ch = 0; ch < NE / 32; ++ch) {
        float ev[32];
        const float4* r4 = (const float4*)(row + ch * 32);
#pragma unroll
        for (int k = 0; k < 8; ++k) {
            float4 v = r4[k];
            ev[4*k+0] = v.x; ev[4*k+1] = v.y; ev[4*k+2] = v.z; ev[4*k+3] = v.w;
        }
#pragma unroll
        for (int c = 0; c < NC; ++c) {
            const float* __restrict__ wr = w + c * NE + ch * 32;
            float a0 = 0.f, a1 = 0.f, a2 = 0.f, a3 = 0.f;
#pragma unroll
            for (int j = 0; j < 32; j += 4) {
                a0 = fmaf(ev[j+0], wr[j+0], a0);
                a1 = fmaf(ev[j+1], wr[j+1], a1);
                a2 = fmaf(ev[j+2], wr[j+2], a2);
                a3 = fmaf(ev[j+3], wr[j+3], a3);
            }
            acc[c] += (a0 + a1) + (a2 + a3);
        }
    }

    float* __restrict__ o = out + (size_t)token * NC;
#pragma unroll
    for (int c = 0; c < NC; c += 4) {
        *(float4*)(o + c) = make_float4(acc[c], acc[c+1], acc[c+2], acc[c+3]);
    }
}

// ---------------------------------------------------------------------------
// Kernel 2: CRF log-likelihood. One wave per batch, lane = destination class.
// Forward recursion in scaled-probability space:
//   a'[c'] = exp(logit_t[c']) * sum_c a[c] * P[c,c'],  P = exp(trans)
// with max-rescaling every 8 steps (log2-scale accumulated in S2).
// ---------------------------------------------------------------------------
__device__ __forceinline__ float readlane_f(float v, int l) {
    return __uint_as_float(__builtin_amdgcn_readlane(__float_as_uint(v), l));
}

__device__ __forceinline__ void crf_step(float& a, const float (&Pc)[NC], float lgv) {
    float a0 = 0.f, a1 = 0.f, a2 = 0.f, a3 = 0.f;
#pragma unroll
    for (int c = 0; c < NC; c += 4) {
        a0 = fmaf(readlane_f(a, c + 0), Pc[c + 0], a0);
        a1 = fmaf(readlane_f(a, c + 1), Pc[c + 1], a1);
        a2 = fmaf(readlane_f(a, c + 2), Pc[c + 2], a2);
        a3 = fmaf(readlane_f(a, c + 3), Pc[c + 3], a3);
    }
    a = ((a0 + a1) + (a2 + a3)) * exp2f(lgv * L2E);
}

__device__ __forceinline__ void crf_rescale(float& a, float& S2) {
    float m = a;
#pragma unroll
    for (int o_ = 32; o_; o_ >>= 1) m = fmaxf(m, __shfl_xor(m, o_));
    a = a * (1.0f / m);
    S2 += log2f(m);
}

__global__ __launch_bounds__(64) void crf_kernel(
    const int* __restrict__ labels,
    const float* __restrict__ logits,
    const float* __restrict__ start_t,
    const float* __restrict__ end_t,
    const float* __restrict__ trans,
    float* __restrict__ out_scalar)
{
    const int b = blockIdx.x;
    const int lane = threadIdx.x;
    const int* __restrict__ lab = labels + b * NT;
    const float* __restrict__ lgp = logits + (size_t)b * NT * NC;

    // ---- numerator: emit sum + transition sum, lane-parallel over t ----
    float nsum = 0.f;
#pragma unroll
    for (int i = 0; i < NT / 64; ++i) {
        const int t = i * 64 + lane;
        const int l = lab[t];
        nsum += lgp[t * NC + l];
        if (t > 0) nsum += trans[lab[t - 1] * NC + l];
    }
#pragma unroll
    for (int o_ = 32; o_; o_ >>= 1) nsum += __shfl_xor(nsum, o_);
    // lane 0 now holds emit+tr total

    // ---- forward scan ----
    const int cp = lane;
    const bool act = lane < NC;

    float Pc[NC];
#pragma unroll
    for (int c = 0; c < NC; ++c)
        Pc[c] = act ? exp2f(trans[c * NC + cp] * L2E) : 0.f;

    float a = act ? exp2f((start_t[cp] + lgp[cp]) * L2E) : 0.f;
    float S2 = 0.f;

    float cur[8], nxt[8];
#pragma unroll
    for (int j = 0; j < 8; ++j) nxt[j] = act ? lgp[j * NC + cp] : 0.f;

    // group 0: steps t = 1..7 (prefetch group 1 first)
#pragma unroll
    for (int j = 0; j < 8; ++j) cur[j] = nxt[j];
#pragma unroll
    for (int j = 0; j < 8; ++j) nxt[j] = act ? lgp[(8 + j) * NC + cp] : 0.f;
#pragma unroll
    for (int j = 1; j < 8; ++j) crf_step(a, Pc, cur[j]);
    crf_rescale(a, S2);

    // groups 1..127: 8 steps each, prefetch one group ahead
#pragma unroll 1
    for (int g = 1; g < NT / 8; ++g) {
#pragma unroll
        for (int j = 0; j < 8; ++j) cur[j] = nxt[j];
        if (g < NT / 8 - 1) {
#pragma unroll
            for (int j = 0; j < 8; ++j)
                nxt[j] = act ? lgp[((g + 1) * 8 + j) * NC + cp] : 0.f;
        }
#pragma unroll
        for (int j = 0; j < 8; ++j) crf_step(a, Pc, cur[j]);
        crf_rescale(a, S2);
    }

    // log_z = (S2 + log2(sum_c a[c]*exp(end[c]))) * ln2
    float pe = act ? a * exp2f(end_t[cp] * L2E) : 0.f;
#pragma unroll
    for (int o_ = 32; o_; o_ >>= 1) pe += __shfl_xor(pe, o_);

    if (lane == 0) {
        const float logz = (S2 + log2f(pe)) * LN2;
        const float numer = nsum + start_t[lab[0]] + end_t[lab[NT - 1]];
        atomicAdd(out_scalar, logz - numer);  // output is -llh summed over b
    }
}

// ---------------------------------------------------------------------------
extern "C" void kernel_launch(void* const* d_in, const int* in_sizes, int n_in,
                              void* d_out, int out_size, void* d_ws, size_t ws_size,
                              hipStream_t stream) {
    const int*   x       = (const int*)d_in[0];
    const int*   labels  = (const int*)d_in[1];
    const float* emb     = (const float*)d_in[2];
    const float* fc_w    = (const float*)d_in[3];
    const float* fc_b    = (const float*)d_in[4];
    const float* start_t = (const float*)d_in[5];
    const float* end_t   = (const float*)d_in[6];
    const float* trans   = (const float*)d_in[7];

    float* out = (float*)d_out;
    float* out_scalar = out + (size_t)NB * NT * NC;

    hipMemsetAsync(out_scalar, 0, sizeof(float), stream);
    logits_kernel<<<NB * NT / 64, 64, 0, stream>>>(x, emb, fc_w, fc_b, out);
    crf_kernel<<<NB, 64, 0, stream>>>(labels, out, start_t, end_t, trans, out_scalar);
}

// Round 2
// 293.222 us; speedup vs baseline: 1.7373x; 1.7373x over previous
//
#include <hip/hip_runtime.h>
#include <hip/hip_bf16.h>
#include <math.h>

#define NV 50257
#define NE 256
#define NC 48
#define NB 64
#define NT 1024
#define L2E 1.44269504088896340736f
#define LN2 0.69314718055994530942f

// ---------------------------------------------------------------------------
// Kernel 1: logits[b,t,c] = emb_table[x[b,t]] . fc_w[c] + fc_b[c]
// One lane per token. fc_w staged in LDS once per block; per-class reads are
// wave-uniform LDS addresses -> broadcast ds_read_b128, conflict-free.
// ---------------------------------------------------------------------------
__global__ __launch_bounds__(256) void logits_kernel(
    const int* __restrict__ x,
    const float* __restrict__ emb,
    const float* __restrict__ w,
    const float* __restrict__ bias,
    float* __restrict__ out)
{
    __shared__ float ws[NC * NE];   // 48 KB
    __shared__ float bs[NC];

    const int tid = threadIdx.x;
#pragma unroll
    for (int i = 0; i < NC * NE / 4 / 256; ++i) {
        const int k = i * 256 + tid;
        ((float4*)ws)[k] = ((const float4*)w)[k];
    }
    if (tid < NC) bs[tid] = bias[tid];
    __syncthreads();

    const int token = blockIdx.x * 256 + tid;
    const int idx = x[token];
    const float* __restrict__ row = emb + (size_t)idx * NE;

    float acc[NC];
#pragma unroll
    for (int c = 0; c < NC; ++c) acc[c] = bs[c];

#pragma unroll 1
    for (int ch = 0; ch < NE / 32; ++ch) {
        float ev[32];
        const float4* r4 = (const float4*)(row + ch * 32);
#pragma unroll
        for (int k = 0; k < 8; ++k) {
            float4 v = r4[k];
            ev[4*k+0] = v.x; ev[4*k+1] = v.y; ev[4*k+2] = v.z; ev[4*k+3] = v.w;
        }
#pragma unroll
        for (int c = 0; c < NC; ++c) {
            const float4* __restrict__ wr4 = (const float4*)(ws + c * NE + ch * 32);
            float a0 = 0.f, a1 = 0.f, a2 = 0.f, a3 = 0.f;
#pragma unroll
            for (int q = 0; q < 8; ++q) {
                float4 wv = wr4[q];
                a0 = fmaf(ev[4*q+0], wv.x, a0);
                a1 = fmaf(ev[4*q+1], wv.y, a1);
                a2 = fmaf(ev[4*q+2], wv.z, a2);
                a3 = fmaf(ev[4*q+3], wv.w, a3);
            }
            acc[c] += (a0 + a1) + (a2 + a3);
        }
    }

    float* __restrict__ o = out + (size_t)token * NC;
#pragma unroll
    for (int c = 0; c < NC; c += 4) {
        *(float4*)(o + c) = make_float4(acc[c], acc[c+1], acc[c+2], acc[c+3]);
    }
}

// ---------------------------------------------------------------------------
// Kernel 2: CRF log-likelihood. One wave per batch, lane = destination class.
// Scaled-probability recursion: a'[c'] = E_t[c'] * sum_c a[c] * P[c,c'].
// Step is phase-split: 48 readlanes -> sched_barrier -> 48 FMAs, so the
// VALU->SGPR->VALU hazard is paid once per step, not 48 times.
// ---------------------------------------------------------------------------
__device__ __forceinline__ float readlane_f(float v, int l) {
    return __uint_as_float(__builtin_amdgcn_readlane(__float_as_uint(v), l));
}

__device__ __forceinline__ void crf_step(float& a, const float (&Pc)[NC], float E) {
    float s[NC];
#pragma unroll
    for (int c = 0; c < NC; ++c) s[c] = readlane_f(a, c);
    __builtin_amdgcn_sched_barrier(0);
    float a0 = 0.f, a1 = 0.f, a2 = 0.f, a3 = 0.f;
#pragma unroll
    for (int c = 0; c < NC; c += 4) {
        a0 = fmaf(s[c + 0], Pc[c + 0], a0);
        a1 = fmaf(s[c + 1], Pc[c + 1], a1);
        a2 = fmaf(s[c + 2], Pc[c + 2], a2);
        a3 = fmaf(s[c + 3], Pc[c + 3], a3);
    }
    a = ((a0 + a1) + (a2 + a3)) * E;
}

__device__ __forceinline__ void crf_rescale(float& a, float& S2) {
    float m = a;
#pragma unroll
    for (int o_ = 32; o_; o_ >>= 1) m = fmaxf(m, __shfl_xor(m, o_));
    a = a * (1.0f / m);
    S2 += log2f(m);
}

__global__ __launch_bounds__(64) void crf_kernel(
    const int* __restrict__ labels,
    const float* __restrict__ logits,
    const float* __restrict__ start_t,
    const float* __restrict__ end_t,
    const float* __restrict__ trans,
    float* __restrict__ out_scalar)
{
    const int b = blockIdx.x;
    const int lane = threadIdx.x;
    const int* __restrict__ lab = labels + b * NT;
    const float* __restrict__ lgp = logits + (size_t)b * NT * NC;

    // ---- numerator: emit sum + transition sum, lane-parallel over t ----
    float nsum = 0.f;
#pragma unroll
    for (int i = 0; i < NT / 64; ++i) {
        const int t = i * 64 + lane;
        const int l = lab[t];
        nsum += lgp[t * NC + l];
        if (t > 0) nsum += trans[lab[t - 1] * NC + l];
    }
#pragma unroll
    for (int o_ = 32; o_; o_ >>= 1) nsum += __shfl_xor(nsum, o_);

    // ---- forward scan ----
    const int cp = lane;
    const bool act = lane < NC;
    // clamped class pointer: always in-bounds; lanes >= NC read class 47's
    // logits but their a is identically 0 (Pc == 0), so values are dead.
    const float* __restrict__ lgc = lgp + (act ? cp : NC - 1);

    float Pc[NC];
#pragma unroll
    for (int c = 0; c < NC; ++c)
        Pc[c] = act ? exp2f(trans[c * NC + cp] * L2E) : 0.f;

    float S2 = 0.f;

    float nxt[8], E[8];
#pragma unroll
    for (int j = 0; j < 8; ++j) nxt[j] = lgc[j * NC];          // t = 0..7

    float a = act ? exp2f((start_t[cp] + nxt[0]) * L2E) : 0.f; // t = 0

    // group 0: steps t = 1..7
#pragma unroll
    for (int j = 1; j < 8; ++j) E[j] = exp2f(nxt[j] * L2E);
#pragma unroll
    for (int j = 0; j < 8; ++j) nxt[j] = lgc[(8 + j) * NC];    // prefetch t=8..15
#pragma unroll
    for (int j = 1; j < 8; ++j) crf_step(a, Pc, E[j]);

    // groups 1..127: 8 steps each; rescale every 16 steps (growth <= 6.25
    // bits/step -> <= 100 bits between rescales, safe in f32)
#pragma unroll 1
    for (int g = 1; g < NT / 8; ++g) {
#pragma unroll
        for (int j = 0; j < 8; ++j) E[j] = exp2f(nxt[j] * L2E);
        if (g < NT / 8 - 1) {
#pragma unroll
            for (int j = 0; j < 8; ++j) nxt[j] = lgc[((g + 1) * 8 + j) * NC];
        }
#pragma unroll
        for (int j = 0; j < 8; ++j) crf_step(a, Pc, E[j]);
        if (g & 1) crf_rescale(a, S2);
    }

    // log_z = (S2 + log2(sum_c a[c]*exp(end[c]))) * ln2
    float pe = act ? a * exp2f(end_t[cp] * L2E) : 0.f;
#pragma unroll
    for (int o_ = 32; o_; o_ >>= 1) pe += __shfl_xor(pe, o_);

    if (lane == 0) {
        const float logz = (S2 + log2f(pe)) * LN2;
        const float numer = nsum + start_t[lab[0]] + end_t[lab[NT - 1]];
        atomicAdd(out_scalar, logz - numer);  // output is -llh summed over b
    }
}

// ---------------------------------------------------------------------------
extern "C" void kernel_launch(void* const* d_in, const int* in_sizes, int n_in,
                              void* d_out, int out_size, void* d_ws, size_t ws_size,
                              hipStream_t stream) {
    const int*   x       = (const int*)d_in[0];
    const int*   labels  = (const int*)d_in[1];
    const float* emb     = (const float*)d_in[2];
    const float* fc_w    = (const float*)d_in[3];
    const float* fc_b    = (const float*)d_in[4];
    const float* start_t = (const float*)d_in[5];
    const float* end_t   = (const float*)d_in[6];
    const float* trans   = (const float*)d_in[7];

    float* out = (float*)d_out;
    float* out_scalar = out + (size_t)NB * NT * NC;

    hipMemsetAsync(out_scalar, 0, sizeof(float), stream);
    logits_kernel<<<NB * NT / 256, 256, 0, stream>>>(x, emb, fc_w, fc_b, out);
    crf_kernel<<<NB, 64, 0, stream>>>(labels, out, start_t, end_t, trans, out_scalar);
}

// Round 3
// 131.506 us; speedup vs baseline: 3.8736x; 2.2297x over previous
//
#include <hip/hip_runtime.h>
#include <hip/hip_bf16.h>
#include <math.h>

#define NV 50257
#define NE 256
#define NC 48
#define NB 64
#define NT 1024
#define NCHUNK 31
#define CL 33   // matvec steps per chunk; 31*33 = 1023 = NT-1
#define L2E 1.44269504088896340736f
#define LN2 0.69314718055994530942f

typedef __attribute__((ext_vector_type(8)))  short bf16x8;
typedef __attribute__((ext_vector_type(16))) float f32x16;

__device__ __forceinline__ unsigned pk_bf16(float lo, float hi) {
    unsigned r;
    asm("v_cvt_pk_bf16_f32 %0, %1, %2" : "=v"(r) : "v"(lo), "v"(hi));
    return r;
}
__device__ __forceinline__ bf16x8 make_bf16x8(const unsigned u[4]) {
    union { unsigned u[4]; bf16x8 v; } t;
    t.u[0] = u[0]; t.u[1] = u[1]; t.u[2] = u[2]; t.u[3] = u[3];
    return t.v;
}
__device__ __forceinline__ float readlane_f(float v, int l) {
    return __uint_as_float(__builtin_amdgcn_readlane(__float_as_uint(v), l));
}

// ---------------------------------------------------------------------------
// Kernel 1: logits[b,t,c] = emb[x[b,t]] . fc_w[c] + fc_b[c]
// Register-tiled GEMM: block = 256 tokens; A ([k][t] transposed) + w ([k][c]
// transposed) in LDS; each lane computes 4 tokens x 12 classes -> 48 FMA per
// 4 LDS b128 reads (VALU-bound). Also emits normalized exp-table E (64-padded)
// and per-(b,t) log2-scale s for the MFMA scan.
// ---------------------------------------------------------------------------
__global__ __launch_bounds__(256) void logits_kernel(
    const int* __restrict__ x, const float* __restrict__ emb,
    const float* __restrict__ w, const float* __restrict__ bias,
    float* __restrict__ out, float* __restrict__ Ef32, float* __restrict__ s_tab)
{
    __shared__ float As[64 * 256];   // [k][t]  64 KB
    __shared__ float Bs[256 * 48];   // [k][c]  48 KB
    __shared__ float bsh[NC];

    const int tid = threadIdx.x;
    const int base = blockIdx.x * 256;

    // stage w transposed: Bs[k][c] = w[c][k]
#pragma unroll
    for (int i = 0; i < 12; ++i) {
        int idx = tid * 12 + i;               // 0..3071 quads
        int c = idx >> 6, kq = idx & 63;
        float4 v = ((const float4*)w)[c * 64 + kq];
        Bs[(4 * kq + 0) * 48 + c] = v.x;
        Bs[(4 * kq + 1) * 48 + c] = v.y;
        Bs[(4 * kq + 2) * 48 + c] = v.z;
        Bs[(4 * kq + 3) * 48 + c] = v.w;
    }
    if (tid < NC) bsh[tid] = bias[tid];

    const int token = base + tid;
    const float4* row4 = (const float4*)(emb + (size_t)x[token] * NE);

    const int wv = tid >> 6, lane = tid & 63;
    const int tg = lane >> 2, cg = lane & 3;

    __syncthreads();

    float acc[4][12];
#pragma unroll
    for (int i = 0; i < 4; ++i)
#pragma unroll
        for (int j = 0; j < 12; ++j) acc[i][j] = bsh[cg * 12 + j];

#pragma unroll 1
    for (int ch = 0; ch < 4; ++ch) {
        if (ch) __syncthreads();
        // stage A transposed: As[k][t] (writes: bank = tid%32, 2-way, free)
#pragma unroll
        for (int u = 0; u < 16; ++u) {
            float4 v = row4[ch * 16 + u];
            As[(4 * u + 0) * 256 + tid] = v.x;
            As[(4 * u + 1) * 256 + tid] = v.y;
            As[(4 * u + 2) * 256 + tid] = v.z;
            As[(4 * u + 3) * 256 + tid] = v.w;
        }
        __syncthreads();
        const float* ap = As + wv * 64 + tg * 4;
        const float* bp = Bs + (size_t)ch * 64 * 48 + cg * 12;
#pragma unroll 4
        for (int k = 0; k < 64; ++k) {
            float4 a4 = *(const float4*)(ap + k * 256);
            float4 b0 = *(const float4*)(bp + k * 48 + 0);
            float4 b1 = *(const float4*)(bp + k * 48 + 4);
            float4 b2 = *(const float4*)(bp + k * 48 + 8);
            float av[4] = {a4.x, a4.y, a4.z, a4.w};
            float bv[12] = {b0.x, b0.y, b0.z, b0.w,
                            b1.x, b1.y, b1.z, b1.w,
                            b2.x, b2.y, b2.z, b2.w};
#pragma unroll
            for (int i = 0; i < 4; ++i)
#pragma unroll
                for (int j = 0; j < 12; ++j)
                    acc[i][j] = fmaf(av[i], bv[j], acc[i][j]);
        }
    }

    const int tok0 = base + wv * 64 + tg * 4;
#pragma unroll
    for (int i = 0; i < 4; ++i) {
        const int tok = tok0 + i;
        float* op = out + (size_t)tok * NC + cg * 12;
        *(float4*)(op + 0) = make_float4(acc[i][0], acc[i][1], acc[i][2], acc[i][3]);
        *(float4*)(op + 4) = make_float4(acc[i][4], acc[i][5], acc[i][6], acc[i][7]);
        *(float4*)(op + 8) = make_float4(acc[i][8], acc[i][9], acc[i][10], acc[i][11]);

        // row max over 48 classes (12 local + reduce over the 4 cg lanes)
        float m = acc[i][0];
#pragma unroll
        for (int j = 1; j < 12; ++j) m = fmaxf(m, acc[i][j]);
        m = fmaxf(m, __shfl_xor(m, 1));
        m = fmaxf(m, __shfl_xor(m, 2));
        const float s = m * L2E;

        float* epr = Ef32 + (size_t)tok * 64 + cg * 12;
        float e[12];
#pragma unroll
        for (int j = 0; j < 12; ++j) e[j] = exp2f(acc[i][j] * L2E - s);
        *(float4*)(epr + 0) = make_float4(e[0], e[1], e[2], e[3]);
        *(float4*)(epr + 4) = make_float4(e[4], e[5], e[6], e[7]);
        *(float4*)(epr + 8) = make_float4(e[8], e[9], e[10], e[11]);
        if (cg == 3) {   // zero-pad classes 48..63
            float* zp = Ef32 + (size_t)tok * 64 + 48;
            float4 z = make_float4(0.f, 0.f, 0.f, 0.f);
            *(float4*)(zp + 0) = z; *(float4*)(zp + 4) = z;
            *(float4*)(zp + 8) = z; *(float4*)(zp + 12) = z;
        }
        if (cg == 0) s_tab[tok] = s;
    }
}

// ---------------------------------------------------------------------------
// Kernel 2: chunked matrix scan. Chunk j of batch b computes
//   C_j = diag(E_{t0+33}) * P^T*D_{t0+32}*P^T*...*D_{t0+1}*P^T   (t0 = 33j)
// as 32 MFMA steps W <- P^T * (diag(E)*W), W_1 = P^T, on 64x64 (48-padded)
// bf16 tiles. D-layout rows (reg&3)+8(reg>>2)+4h align with the stacked-halves
// B-operand k-layout -> D->B is pure cvt_pk (no cross-lane movement).
// ---------------------------------------------------------------------------
__global__ __launch_bounds__(64) void scan_kernel(
    const float* __restrict__ trans, const float* __restrict__ Ef32,
    const float* __restrict__ s_tab, unsigned* __restrict__ Cpk,
    float* __restrict__ S2tab)
{
    const int j = blockIdx.x;        // chunk 0..30
    const int b = blockIdx.y;        // batch
    const int lane = threadIdx.x;
    const int h = lane >> 5;
    const int l31 = lane & 31;
    const int t0 = j * CL;

    __shared__ __align__(16) float El[CL * 64];   // E rows t0+1 .. t0+33

    const float* esrc = Ef32 + ((size_t)b * NT + t0 + 1) * 64;
#pragma unroll
    for (int r = 0; r < CL; ++r) El[r * 64 + lane] = esrc[r * 64 + lane];
    __syncthreads();

    // A = P^T as constant bf16 A-fragments: A[r][k] = exp(trans[k][r])
    bf16x8 A[2][4];
#pragma unroll
    for (int rt = 0; rt < 2; ++rt) {
        const int r = l31 + 32 * rt;
#pragma unroll
        for (int kf = 0; kf < 4; ++kf) {
            unsigned ua[4];
#pragma unroll
            for (int p = 0; p < 4; ++p) {
                const int i0 = 2 * p;
                const int k0 = 16 * kf + 4 * h + (i0 & 3) + 8 * (i0 >> 2);
                const int k1 = k0 + 1;
                float v0 = (r < NC && k0 < NC) ? exp2f(trans[k0 * NC + r] * L2E) : 0.f;
                float v1 = (r < NC && k1 < NC) ? exp2f(trans[k1 * NC + r] * L2E) : 0.f;
                ua[p] = pk_bf16(v0, v1);
            }
            A[rt][kf] = make_bf16x8(ua);
        }
    }

    // acc = W_1 = P^T in D-layout
    f32x16 acc[2][2];
#pragma unroll
    for (int rt = 0; rt < 2; ++rt)
#pragma unroll
        for (int ct = 0; ct < 2; ++ct)
#pragma unroll
            for (int reg = 0; reg < 16; ++reg) {
                const int rw = 32 * rt + (reg & 3) + 8 * (reg >> 2) + 4 * h;
                const int cl = 32 * ct + l31;
                acc[rt][ct][reg] =
                    (rw < NC && cl < NC) ? exp2f(trans[cl * NC + rw] * L2E) : 0.f;
            }

    f32x16 Z;
#pragma unroll
    for (int i = 0; i < 16; ++i) Z[i] = 0.f;

    float S2 = 88.f;   // static 2^-88 shift applied at s==17
#pragma unroll 1
    for (int s = 1; s <= 32; ++s) {
        const float* ep = El + (s - 1) * 64;
        bf16x8 B[4][2];
#pragma unroll
        for (int kf = 0; kf < 4; ++kf) {
            float4 e0 = *(const float4*)(ep + 16 * kf + 4 * h);
            float4 e1 = *(const float4*)(ep + 16 * kf + 8 + 4 * h);
            if (s == 17) {
                e0.x *= 0x1p-88f; e0.y *= 0x1p-88f; e0.z *= 0x1p-88f; e0.w *= 0x1p-88f;
                e1.x *= 0x1p-88f; e1.y *= 0x1p-88f; e1.z *= 0x1p-88f; e1.w *= 0x1p-88f;
            }
            const int rt = kf >> 1, q = 8 * (kf & 1);
#pragma unroll
            for (int ct = 0; ct < 2; ++ct) {
                unsigned u[4];
                u[0] = pk_bf16(acc[rt][ct][q + 0] * e0.x, acc[rt][ct][q + 1] * e0.y);
                u[1] = pk_bf16(acc[rt][ct][q + 2] * e0.z, acc[rt][ct][q + 3] * e0.w);
                u[2] = pk_bf16(acc[rt][ct][q + 4] * e1.x, acc[rt][ct][q + 5] * e1.y);
                u[3] = pk_bf16(acc[rt][ct][q + 6] * e1.z, acc[rt][ct][q + 7] * e1.w);
                B[kf][ct] = make_bf16x8(u);
            }
        }
#pragma unroll
        for (int rt = 0; rt < 2; ++rt)
#pragma unroll
            for (int ct = 0; ct < 2; ++ct) {
                f32x16 d = __builtin_amdgcn_mfma_f32_32x32x16_bf16(A[rt][0], B[0][ct], Z, 0, 0, 0);
                d = __builtin_amdgcn_mfma_f32_32x32x16_bf16(A[rt][1], B[1][ct], d, 0, 0, 0);
                d = __builtin_amdgcn_mfma_f32_32x32x16_bf16(A[rt][2], B[2][ct], d, 0, 0, 0);
                d = __builtin_amdgcn_mfma_f32_32x32x16_bf16(A[rt][3], B[3][ct], d, 0, 0, 0);
                acc[rt][ct] = d;
            }
    }

    // final: C = diag(E_{t0+33}) * W  (row scaling)
    const float* ef = El + 32 * 64;
#pragma unroll
    for (int rt = 0; rt < 2; ++rt)
#pragma unroll
        for (int g = 0; g < 4; ++g) {
            float4 e = *(const float4*)(ef + 32 * rt + 8 * g + 4 * h);
#pragma unroll
            for (int ct = 0; ct < 2; ++ct) {
                acc[rt][ct][4 * g + 0] *= e.x;
                acc[rt][ct][4 * g + 1] *= e.y;
                acc[rt][ct][4 * g + 2] *= e.z;
                acc[rt][ct][4 * g + 3] *= e.w;
            }
        }

    // normalize by max, accumulate log2 scale + per-step logit scales
    float m = acc[0][0][0];
#pragma unroll
    for (int rt = 0; rt < 2; ++rt)
#pragma unroll
        for (int ct = 0; ct < 2; ++ct)
#pragma unroll
            for (int reg = 0; reg < 16; ++reg) m = fmaxf(m, acc[rt][ct][reg]);
#pragma unroll
    for (int o = 32; o; o >>= 1) m = fmaxf(m, __shfl_xor(m, o));
    const float inv = 1.f / m;
    S2 += log2f(m);
    float sv = (lane < CL) ? s_tab[(size_t)b * NT + t0 + 1 + lane] : 0.f;
#pragma unroll
    for (int o = 32; o; o >>= 1) sv += __shfl_xor(sv, o);
    S2 += sv;
    if (lane == 0) S2tab[b * NCHUNK + j] = S2;

    // store bf16, row-pair-packed: u32 @ [rowpair][col] (coalesced)
    unsigned* cbase = Cpk + (((size_t)b * NCHUNK + j) << 11);
#pragma unroll
    for (int rt = 0; rt < 2; ++rt)
#pragma unroll
        for (int ct = 0; ct < 2; ++ct)
#pragma unroll
            for (int g = 0; g < 4; ++g)
#pragma unroll
                for (int pp = 0; pp < 2; ++pp) {
                    const int reg = 4 * g + 2 * pp;
                    unsigned u = pk_bf16(acc[rt][ct][reg] * inv, acc[rt][ct][reg + 1] * inv);
                    const int rw = 32 * rt + 2 * pp + 8 * g + 4 * h;   // even row
                    cbase[(rw >> 1) * 64 + 32 * ct + l31] = u;
                }
}

// ---------------------------------------------------------------------------
// Kernel 3: combine — per batch: a <- C_k * a over 31 chunks (readlane matvec,
// double-buffered chunk loads), plus numerator and final log_z.
// ---------------------------------------------------------------------------
__device__ __forceinline__ void comb_load(const unsigned* __restrict__ cb, int k,
                                          uint4* __restrict__ buf) {
    const uint4* p = (const uint4*)cb + (size_t)k * 512;
#pragma unroll
    for (int q = 0; q < 16; ++q) buf[q] = p[q];
}

__device__ __forceinline__ void comb_step(const uint4* __restrict__ buf,
                                          float& a, float& S2, unsigned sh) {
    float sreg[64];
#pragma unroll
    for (int c = 0; c < 64; ++c) sreg[c] = readlane_f(a, c);
    __builtin_amdgcn_sched_barrier(0);
    float a0 = 0.f, a1 = 0.f, a2 = 0.f, a3 = 0.f;
#pragma unroll
    for (int q = 0; q < 16; ++q) {
        uint4 u = buf[q];
        a0 = fmaf(__uint_as_float((u.x << sh) & 0xffff0000u), sreg[4 * q + 0], a0);
        a1 = fmaf(__uint_as_float((u.y << sh) & 0xffff0000u), sreg[4 * q + 1], a1);
        a2 = fmaf(__uint_as_float((u.z << sh) & 0xffff0000u), sreg[4 * q + 2], a2);
        a3 = fmaf(__uint_as_float((u.w << sh) & 0xffff0000u), sreg[4 * q + 3], a3);
    }
    a = (a0 + a1) + (a2 + a3);
    float mm = a;
#pragma unroll
    for (int o = 32; o; o >>= 1) mm = fmaxf(mm, __shfl_xor(mm, o));
    a *= 1.f / mm;
    S2 += log2f(mm);
}

__global__ __launch_bounds__(64) void combine_kernel(
    const int* __restrict__ labels, const float* __restrict__ logits,
    const float* __restrict__ start_t, const float* __restrict__ end_t,
    const float* __restrict__ trans, const unsigned* __restrict__ Cpk,
    const float* __restrict__ S2tab, float* __restrict__ out_scalar)
{
    const int b = blockIdx.x;
    const int lane = threadIdx.x;
    const int* __restrict__ lab = labels + b * NT;
    const float* __restrict__ lgp = logits + (size_t)b * NT * NC;

    // numerator
    float nsum = 0.f;
#pragma unroll
    for (int i = 0; i < NT / 64; ++i) {
        const int t = i * 64 + lane;
        const int l = lab[t];
        nsum += lgp[t * NC + l];
        if (t > 0) nsum += trans[lab[t - 1] * NC + l];
    }
#pragma unroll
    for (int o = 32; o; o >>= 1) nsum += __shfl_xor(nsum, o);

    // forward: a0, then 31 chunk matvecs
    float a = (lane < NC) ? exp2f((start_t[lane] + lgp[lane]) * L2E) : 0.f;
    float S2 = 0.f;
    const unsigned sh = (lane & 1) ? 0u : 16u;
    const unsigned* cb = Cpk + (((size_t)b * NCHUNK) << 11) + (lane >> 1) * 64;

    uint4 bufA[16], bufB[16];
    comb_load(cb, 0, bufA);
#pragma unroll 1
    for (int k = 0; k < NCHUNK - 1; k += 2) {
        comb_load(cb, k + 1, bufB);
        comb_step(bufA, a, S2, sh);
        if (k + 2 < NCHUNK) comb_load(cb, k + 2, bufA);
        comb_step(bufB, a, S2, sh);
    }
    comb_step(bufA, a, S2, sh);   // chunk 30

    float pe = (lane < NC) ? a * exp2f(end_t[lane] * L2E) : 0.f;
#pragma unroll
    for (int o = 32; o; o >>= 1) pe += __shfl_xor(pe, o);
    float s2k = (lane < NCHUNK) ? S2tab[b * NCHUNK + lane] : 0.f;
#pragma unroll
    for (int o = 32; o; o >>= 1) s2k += __shfl_xor(s2k, o);

    if (lane == 0) {
        const float logz = (S2 + s2k + log2f(pe)) * LN2;
        const float numer = nsum + start_t[lab[0]] + end_t[lab[NT - 1]];
        atomicAdd(out_scalar, logz - numer);
    }
}

// ---------------------------------------------------------------------------
extern "C" void kernel_launch(void* const* d_in, const int* in_sizes, int n_in,
                              void* d_out, int out_size, void* d_ws, size_t ws_size,
                              hipStream_t stream) {
    const int*   x       = (const int*)d_in[0];
    const int*   labels  = (const int*)d_in[1];
    const float* emb     = (const float*)d_in[2];
    const float* fc_w    = (const float*)d_in[3];
    const float* fc_b    = (const float*)d_in[4];
    const float* start_t = (const float*)d_in[5];
    const float* end_t   = (const float*)d_in[6];
    const float* trans   = (const float*)d_in[7];

    float* out = (float*)d_out;
    float* out_scalar = out + (size_t)NB * NT * NC;

    // workspace carve (~33.3 MB total)
    char* ws = (char*)d_ws;
    constexpr size_t EF_BYTES  = (size_t)NB * NT * 64 * 4;       // 16 MB
    constexpr size_t ST_BYTES  = (size_t)NB * NT * 4;            // 256 KB
    constexpr size_t CP_BYTES  = (size_t)NB * NCHUNK * 2048 * 4; // 15.5 MB
    float*    Ef32  = (float*)ws;
    float*    s_tab = (float*)(ws + EF_BYTES);
    unsigned* Cpk   = (unsigned*)(ws + EF_BYTES + ST_BYTES);
    float*    S2tab = (float*)(ws + EF_BYTES + ST_BYTES + CP_BYTES);

    hipMemsetAsync(out_scalar, 0, sizeof(float), stream);
    logits_kernel<<<NB * NT / 256, 256, 0, stream>>>(x, emb, fc_w, fc_b, out, Ef32, s_tab);
    scan_kernel<<<dim3(NCHUNK, NB), 64, 0, stream>>>(trans, Ef32, s_tab, Cpk, S2tab);
    combine_kernel<<<NB, 64, 0, stream>>>(labels, out, start_t, end_t, trans, Cpk, S2tab, out_scalar);
}